// Round 5
// baseline (374.156 us; speedup 1.0000x reference)
//
#include <hip/hip_runtime.h>
#include <math.h>

// Problem constants
#define NPX   1048576      // 1024*1024
#define TD    1025         // tex_eval spatial dim
#define PH    19           // patch height (cells) for 16-tall tile
#define SCELL 19           // strip width in cells (covers 16 px + 3 halo)
#define SROW  (SCELL * 32) // fp16 per strip row (608)
#define DPAD  1028         // padded input spatial dim (rows -2..1025 -> 0..1027)
#define ROWB  65792        // DPAD*32*2 bytes per padded row
// ws layout: [0, 16KB)            ffrag_g fp16 [kk][lane][8] (MFMA B-frag order)
//            [48KB, +33.62MB)     tex     fp16 [y][x][c]  (TD*TD*16)
//            [DP_OFF, +67.63MB)   Dp      fp16 [1028][1028][32] zero-padded CL
#define DP_OFF 33673216

typedef _Float16 half8 __attribute__((ext_vector_type(8)));
typedef float    f32x4 __attribute__((ext_vector_type(4)));

__device__ __forceinline__ void load_lds16(const void* g, void* lds) {
    __builtin_amdgcn_global_load_lds(
        (const __attribute__((address_space(1))) void*)g,
        (__attribute__((address_space(3))) void*)lds, 16, 0, 0);
}

// ------- Stage 1 (fused): repack + MLP in one launch ------------------------
// Blocks [0, 5140): repack data fp32 NCHW -> zero-padded fp16 channel-last Dp.
// Blocks [5140, 5172): MLP -> MFMA B-fragment-ordered fp16 filter ffrag_g.
__global__ __launch_bounds__(256) void repack_mlp_kernel(
    const float* __restrict__ data, _Float16* __restrict__ Dp,
    const float* __restrict__ expr,
    const float* __restrict__ W1, const float* __restrict__ b1,
    const float* __restrict__ W2, const float* __restrict__ b2,
    const float* __restrict__ W3, const float* __restrict__ b3,
    _Float16* __restrict__ ffrag_g)
{
    __shared__ char smem[16384];
    int tid = threadIdx.x;
    int b = blockIdx.x;

    if (b >= 5140) {
        // ---------------- MLP path (32 blocks) ----------------
        float* sx  = (float*)smem;          // 76
        float* sh1 = sx + 80;               // 128
        float* sh2 = sh1 + 128;             // 64
        if (tid < 76) sx[tid] = expr[tid];
        __syncthreads();
        if (tid < 128) {
            float a = b1[tid];
            const float* w = W1 + tid * 76;
            #pragma unroll 4
            for (int i = 0; i < 76; ++i) a += sx[i] * w[i];
            sh1[tid] = a >= 0.f ? a : 0.02f * a;
        }
        __syncthreads();
        if (tid < 64) {
            float a = b2[tid];
            const float* w = W2 + tid * 128;
            #pragma unroll 4
            for (int i = 0; i < 128; ++i) a += sh1[i] * w[i];
            sh2[tid] = a >= 0.f ? a : 0.02f * a;
        }
        __syncthreads();
        int o = (b - 5140) * 256 + tid;      // 0..8191
        float a = b3[o];
        const float* w = W3 + o * 64;
        #pragma unroll 4
        for (int i = 0; i < 64; ++i) a += sh2[i] * w[i];
        a = tanhf(a);
        int oc = o >> 9;
        int ic = (o >> 4) & 31;
        int kk = o & 15;
        ffrag_g[(size_t)(kk * 64 + (ic >> 3) * 16 + oc) * 8 + (ic & 7)] = (_Float16)a;
        return;
    }

    // ---------------- repack path (5140 blocks) ----------------
    _Float16* s = (_Float16*)smem;          // 256*32 fp16 = 16 KB
    int xb = b % 5;
    int Y  = b / 5;
    int X = xb * 256 + tid;
    int y = Y - 2, x = X - 2;
    bool ok = ((unsigned)y < 1024u) && ((unsigned)x < 1024u);
    const float* dp = data + ((size_t)y << 10) + x;

    float v[32];
    #pragma unroll
    for (int j = 0; j < 32; ++j) v[j] = 0.f;
    if (ok) {
        #pragma unroll
        for (int j = 0; j < 32; ++j) v[j] = __builtin_nontemporal_load(&dp[(size_t)j * NPX]);
    }
    #pragma unroll
    for (int g = 0; g < 4; ++g) {
        half8 h;
        #pragma unroll
        for (int j = 0; j < 8; ++j) h[j] = (_Float16)v[g * 8 + j];
        int chunk = tid * 4 + g;
        int sw = chunk ^ ((chunk >> 3) & 7);  // spread banks
        *(half8*)((char*)s + sw * 16) = h;
    }
    __syncthreads();
    char* rowbase = (char*)Dp + (size_t)Y * ROWB + xb * 16384;
    int lim = ROWB - xb * 16384;
    #pragma unroll
    for (int i = 0; i < 4; ++i) {
        int off = tid * 16 + i * 4096;
        if (off < lim) {
            int chunk = tid + i * 256;
            int sw = chunk ^ ((chunk >> 3) & 7);
            *(uint4*)(rowbase + off) = *(uint4*)((char*)s + sw * 16);
        }
    }
}

// ------------- Stage 2: implicit-GEMM conv, x-split pipelined ----------------
// Tile 32(x) x 16(y). Patch split into LEFT (cells 0..18) / RIGHT (cells
// 16..34) strips; DMA of RIGHT overlaps MFMA compute on LEFT.
__device__ __forceinline__ void stage_strip(
    const _Float16* __restrict__ Dp, _Float16* sp,
    int ox0, int oy0, int w, int l, int xoff)
{
    int base = (ox0 + xoff) * 64;
    for (int r = w; r < PH; r += 4) {
        int gy = min(oy0 + r, DPAD - 1);
        const char* grow = (const char*)Dp + (size_t)gy * ROWB;
        char* lrow = (char*)(sp + r * SROW);
        // 19 cells * 64 B = 1216 B per row: 64 lanes + 12 lanes
        int off0 = min(base + l * 16, ROWB - 16);
        load_lds16(grow + off0, lrow);
        if (l < 12) {
            int off1 = min(base + 1024 + l * 16, ROWB - 16);
            load_lds16(grow + off1, lrow + 1024);
        }
    }
}

__device__ __forceinline__ void compute_strip(
    const _Float16* sp, const half8* bfrag, f32x4* acc,
    int w, int lane15, int q)
{
    #pragma unroll 4
    for (int kk = 0; kk < 16; ++kk) {
        int ky = kk >> 2, kx = kk & 3;
        #pragma unroll
        for (int tr = 0; tr < 4; ++tr) {
            int pc = (w * 4 + tr + ky) * SCELL + lane15 + kx;
            half8 af = *(const half8*)&sp[pc * 32 + q * 8];
            acc[tr] = __builtin_amdgcn_mfma_f32_16x16x32_f16(af, bfrag[kk], acc[tr], 0, 0, 0);
        }
    }
}

__global__ __launch_bounds__(256, 3) void conv_mfma_kernel(
    const _Float16* __restrict__ Dp,         // [1028][1028][32] fp16
    const _Float16* __restrict__ ffrag_g,    // [16][64][8] fp16
    _Float16* __restrict__ tex)              // [1025][1025][16] fp16
{
    __shared__ _Float16 spL[PH * SROW];      // 23,104 B
    __shared__ _Float16 spR[PH * SROW];      // 23,104 B

    int tid = threadIdx.x;
    int l = tid & 63, w = tid >> 6;
    int ox0 = blockIdx.x * 32;
    int oy0 = blockIdx.y * 16;
    int lane15 = l & 15;
    int q = l >> 4;

    // filter fragments -> registers (64 VGPR), L2-hot
    half8 bfrag[16];
    #pragma unroll
    for (int kk = 0; kk < 16; ++kk)
        bfrag[kk] = *(const half8*)&ffrag_g[kk * 512 + l * 8];

    f32x4 acc[2][4];
    #pragma unroll
    for (int p = 0; p < 2; ++p)
        #pragma unroll
        for (int t = 0; t < 4; ++t) acc[p][t] = (f32x4){0.f, 0.f, 0.f, 0.f};

    // pipeline: DMA L -> bar -> [issue DMA R | compute L] -> bar -> compute R
    stage_strip(Dp, spL, ox0, oy0, w, l, 0);
    __syncthreads();                          // drain: left ready
    stage_strip(Dp, spR, ox0, oy0, w, l, 16); // in flight during compute L
    compute_strip(spL, bfrag, acc[0], w, lane15, q);
    __syncthreads();                          // right DMAs long done -> cheap
    compute_strip(spR, bfrag, acc[1], w, lane15, q);

    // epilogue: C/D layout col = lane&15 (oc), row = q*4 + reg
    #pragma unroll
    for (int p = 0; p < 2; ++p) {
        #pragma unroll
        for (int tr = 0; tr < 4; ++tr) {
            int oy = oy0 + w * 4 + tr;
            if (oy > 1024) continue;
            int pxb = ox0 + p * 16 + q * 4;
            #pragma unroll
            for (int r = 0; r < 4; ++r) {
                int px = pxb + r;
                if (px > 1024) continue;
                tex[((size_t)oy * TD + px) * 16 + lane15] = (_Float16)acc[p][tr][r];
            }
        }
    }
}

// ---------------- Stage 3: bilinear grid-sample (border pad) -----------------
// 1 px/thread, minimal VGPR -> max resident waves (gather-latency hiding).
// All 8 texel loads issued before any use; nontemporal uv/out (stream-once).
__global__ __launch_bounds__(256, 6) void sample_kernel(
    const float* __restrict__ uv,            // [2][1024][1024]
    const _Float16* __restrict__ tex,        // [1025][1025][16] fp16
    float* __restrict__ out)                 // [16][1024][1024]
{
    int p = blockIdx.x * 256 + threadIdx.x;  // 0..NPX-1
    float x = __builtin_nontemporal_load(&uv[p]);
    float y = __builtin_nontemporal_load(&uv[NPX + p]);
    float ix = fminf(fmaxf(((x + 1.f) * 1025.f - 1.f) * 0.5f, 0.f), 1024.f);
    float iy = fminf(fmaxf(((y + 1.f) * 1025.f - 1.f) * 0.5f, 0.f), 1024.f);
    float fx0 = floorf(ix), fy0 = floorf(iy);
    float wx = ix - fx0, wy = iy - fy0;
    int x0 = (int)fx0, y0 = (int)fy0;
    int x1 = min(x0 + 1, 1024), y1 = min(y0 + 1, 1024);

    const half8* t00 = (const half8*)(tex + ((size_t)y0 * TD + x0) * 16);
    const half8* t01 = (const half8*)(tex + ((size_t)y0 * TD + x1) * 16);
    const half8* t10 = (const half8*)(tex + ((size_t)y1 * TD + x0) * 16);
    const half8* t11 = (const half8*)(tex + ((size_t)y1 * TD + x1) * 16);

    half8 v0 = t00[0], v1 = t00[1];
    half8 v2 = t01[0], v3 = t01[1];
    half8 v4 = t10[0], v5 = t10[1];
    half8 v6 = t11[0], v7 = t11[1];

    float w00 = (1.f - wx) * (1.f - wy);
    float w01 = wx * (1.f - wy);
    float w10 = (1.f - wx) * wy;
    float w11 = wx * wy;

    #pragma unroll
    for (int c = 0; c < 8; ++c) {
        float r0 = (float)v0[c] * w00 + (float)v2[c] * w01
                 + (float)v4[c] * w10 + (float)v6[c] * w11;
        float r1 = (float)v1[c] * w00 + (float)v3[c] * w01
                 + (float)v5[c] * w10 + (float)v7[c] * w11;
        __builtin_nontemporal_store(r0, &out[(size_t)c * NPX + p]);
        __builtin_nontemporal_store(r1, &out[(size_t)(c + 8) * NPX + p]);
    }
}

extern "C" void kernel_launch(void* const* d_in, const int* in_sizes, int n_in,
                              void* d_out, int out_size, void* d_ws, size_t ws_size,
                              hipStream_t stream) {
    const float* expr = (const float*)d_in[0];
    // d_in[1] = audio_features: unused by the reference
    const float* uv   = (const float*)d_in[2];
    const float* data = (const float*)d_in[3];
    const float* W1   = (const float*)d_in[4];
    const float* b1   = (const float*)d_in[5];
    const float* W2   = (const float*)d_in[6];
    const float* b2   = (const float*)d_in[7];
    const float* W3   = (const float*)d_in[8];
    const float* b3   = (const float*)d_in[9];
    float* out = (float*)d_out;

    _Float16* ffrag_g  = (_Float16*)d_ws;                            // 16 KB
    _Float16* tex      = (_Float16*)((char*)d_ws + 49152);           // 33.62 MB
    _Float16* Dp       = (_Float16*)((char*)d_ws + DP_OFF);          // 67.63 MB

    repack_mlp_kernel<<<5140 + 32, 256, 0, stream>>>(
        data, Dp, expr, W1, b1, W2, b2, W3, b3, ffrag_g);
    conv_mfma_kernel<<<dim3(33, 65), 256, 0, stream>>>(Dp, ffrag_g, tex);
    sample_kernel<<<NPX / 256, 256, 0, stream>>>(uv, tex, out);
}